// Round 1
// baseline (702.498 us; speedup 1.0000x reference)
//
#include <hip/hip_runtime.h>
#include <hip/hip_bf16.h>
#include <stdint.h>

// Problem constants (N=32, D_IN=1024, H=2048, D_OUT=256)
#define NP     32
#define P_W1   2097152   // H*D_IN
#define P_B1   2048      // H
#define P_W2   524288    // D_OUT*H
#define P_B2   256       // D_OUT
#define OFFB1  2097152
#define OFFW2  2099200
#define OFFB2  2623488
#define P_TOT  2623744
#define EPS_F  0.1f

typedef short  bf16x8 __attribute__((ext_vector_type(8)));
typedef float  f32x16 __attribute__((ext_vector_type(16)));

// f32 -> bf16 round-to-nearest-even
__device__ __forceinline__ short f2bf(float x) {
    uint32_t u = __builtin_bit_cast(uint32_t, x);
    u += 0x7fffu + ((u >> 16) & 1u);
    return (short)(u >> 16);
}

struct Seg { const float* p; int stride; int off; };

// theta is the virtual concat [W1 | b1 | W2 | b2] per particle. All segment
// boundaries are multiples of 64, so any 64-aligned chunk stays in one segment.
__device__ __forceinline__ Seg seg_of(const float* W1, const float* b1,
                                      const float* W2, const float* b2, int pbase) {
    Seg s;
    if (pbase < OFFB1)      { s.p = W1; s.stride = P_W1; s.off = pbase; }
    else if (pbase < OFFW2) { s.p = b1; s.stride = P_B1; s.off = pbase - OFFB1; }
    else if (pbase < OFFB2) { s.p = W2; s.stride = P_W2; s.off = pbase - OFFW2; }
    else                    { s.p = b2; s.stride = P_B2; s.off = pbase - OFFB2; }
    return s;
}

__global__ void zero_kernel(float* __restrict__ G) {
    G[threadIdx.x] = 0.0f;   // <<<1,1024>>> zeros the 32x32 Gram accumulator
}

// G = theta @ theta^T via 32x32x16 bf16 MFMA. One wave covers the full 32x32
// tile; A and B fragments are the SAME registers (layout-permutation cancels).
__global__ void __launch_bounds__(256)
gram_kernel(const float* __restrict__ W1, const float* __restrict__ b1,
            const float* __restrict__ W2, const float* __restrict__ b2,
            float* __restrict__ G) {
    const int lane   = threadIdx.x & 63;
    const int wave   = (blockIdx.x * 256 + threadIdx.x) >> 6;
    const int nwaves = gridDim.x * 4;
    const int row    = lane & 31;   // theta row this lane loads (= A.m and B.n)
    const int q      = lane >> 5;   // k half-select within fragment

    f32x16 acc;
    #pragma unroll
    for (int r = 0; r < 16; r++) acc[r] = 0.0f;

    for (int c = wave; c < P_TOT / 64; c += nwaves) {
        const int kb = c * 64;                       // 64-float superchunk = 4 MFMA k-chunks
        Seg s = seg_of(W1, b1, W2, b2, kb);
        const float* base = s.p + (size_t)row * s.stride + s.off + q * 8;

        float v[4][8];
        #pragma unroll
        for (int cc = 0; cc < 4; cc++) {
            const float4 lo = *reinterpret_cast<const float4*>(base + cc * 16);
            const float4 hi = *reinterpret_cast<const float4*>(base + cc * 16 + 4);
            v[cc][0] = lo.x; v[cc][1] = lo.y; v[cc][2] = lo.z; v[cc][3] = lo.w;
            v[cc][4] = hi.x; v[cc][5] = hi.y; v[cc][6] = hi.z; v[cc][7] = hi.w;
        }
        #pragma unroll
        for (int cc = 0; cc < 4; cc++) {
            bf16x8 f;
            #pragma unroll
            for (int e = 0; e < 8; e++) f[e] = f2bf(v[cc][e]);
            acc = __builtin_amdgcn_mfma_f32_32x32x16_bf16(f, f, acc, 0, 0, 0);
        }
    }

    // C/D layout (m74/m101): col = lane&31, row = (reg&3) + 8*(reg>>2) + 4*(lane>>5)
    #pragma unroll
    for (int r = 0; r < 16; r++) {
        const int orow = (r & 3) + 8 * (r >> 2) + 4 * q;
        atomicAdd(&G[orow * 32 + row], acc[r]);
    }
}

// M' = M - I (identity applied in exact f32 in the apply epilogue):
// M'[i][j] = (EPS/n)*K[i][j]*[j>=1]  - delta_ij * 3*EPS*S_i/n
__global__ void computeM_kernel(const float* __restrict__ G, float* __restrict__ Mp) {
    __shared__ float Ks[32][32];
    const int t = threadIdx.x;           // <<<1,1024>>>
    const int i = t >> 5, j = t & 31;
    const float sqi = G[i * 33];
    const float sqj = G[j * 33];
    const float d2  = fmaxf(sqi + sqj - 2.0f * G[i * 32 + j], 0.0f);
    const float K   = expf(-0.5f * d2);
    Ks[i][j] = K;
    __syncthreads();
    float S = 0.0f;
    for (int m = 1; m < 32; m++) S += Ks[i][m];
    float v = (j >= 1) ? (EPS_F / 32.0f) * K : 0.0f;
    if (i == j) v -= (3.0f * EPS_F / 32.0f) * S;
    Mp[i * 32 + j] = v;
}

// out = theta + M' @ theta, tile = all 32 rows x 32 positions per wave, via
// two 32x32x16 MFMAs (k = particle index). A-frag (M') is loop-invariant.
__global__ void __launch_bounds__(256)
apply_kernel(const float* __restrict__ W1, const float* __restrict__ b1,
             const float* __restrict__ W2, const float* __restrict__ b2,
             const float* __restrict__ Mp, float* __restrict__ out) {
    const int lane   = threadIdx.x & 63;
    const int wave   = (blockIdx.x * 256 + threadIdx.x) >> 6;
    const int nwaves = gridDim.x * 4;
    const int col    = lane & 31;   // position within tile (B.n / D.col); also A.m for M' load
    const int q      = lane >> 5;

    bf16x8 a0, a1;                  // M'[m][0:16], M'[m][16:32] fragments
    {
        const float* mrow = Mp + col * 32 + q * 8;
        #pragma unroll
        for (int e = 0; e < 8; e++) a0[e] = f2bf(mrow[e]);
        #pragma unroll
        for (int e = 0; e < 8; e++) a1[e] = f2bf(mrow[16 + e]);
    }

    for (int tl = wave; tl < P_TOT / 32; tl += nwaves) {
        const int p0 = tl * 32;
        Seg s = seg_of(W1, b1, W2, b2, p0);
        const float* sp = s.p + s.off + col;
        const int   str = s.stride;

        // B-frag: lane holds theta[k = q*8+e (+16)][p0+col]; each load instr
        // covers 2 full 128B lines (2 rows x 32 consecutive floats).
        float bv[16];
        #pragma unroll
        for (int e = 0; e < 8; e++) bv[e]     = sp[(size_t)(q * 8 + e) * str];
        #pragma unroll
        for (int e = 0; e < 8; e++) bv[8 + e] = sp[(size_t)(16 + q * 8 + e) * str];

        bf16x8 bf0, bf1;
        #pragma unroll
        for (int e = 0; e < 8; e++) bf0[e] = f2bf(bv[e]);
        #pragma unroll
        for (int e = 0; e < 8; e++) bf1[e] = f2bf(bv[8 + e]);

        f32x16 acc;
        #pragma unroll
        for (int r = 0; r < 16; r++) acc[r] = 0.0f;
        acc = __builtin_amdgcn_mfma_f32_32x32x16_bf16(a0, bf0, acc, 0, 0, 0);
        acc = __builtin_amdgcn_mfma_f32_32x32x16_bf16(a1, bf1, acc, 0, 0, 0);

        // Epilogue: out = theta (exact f32, L1-hot reload) + correction
        #pragma unroll
        for (int r = 0; r < 16; r++) {
            const int orow = (r & 3) + 8 * (r >> 2) + 4 * q;
            const float th = sp[(size_t)orow * str];
            out[(size_t)orow * P_TOT + p0 + col] = th + acc[r];
        }
    }
}

extern "C" void kernel_launch(void* const* d_in, const int* in_sizes, int n_in,
                              void* d_out, int out_size, void* d_ws, size_t ws_size,
                              hipStream_t stream) {
    const float* W1 = (const float*)d_in[0];
    const float* b1 = (const float*)d_in[1];
    const float* W2 = (const float*)d_in[2];
    const float* b2 = (const float*)d_in[3];
    // d_in[4] (X) and d_in[5] (y) are unused by the reference computation.
    float* out = (float*)d_out;
    float* G   = (float*)d_ws;          // 1024 floats
    float* Mp  = G + 1024;              // 1024 floats

    zero_kernel<<<1, 1024, 0, stream>>>(G);
    gram_kernel<<<256, 256, 0, stream>>>(W1, b1, W2, b2, G);
    computeM_kernel<<<1, 1024, 0, stream>>>(G, Mp);
    apply_kernel<<<2048, 256, 0, stream>>>(W1, b1, W2, b2, Mp, out);
}